// Round 3
// baseline (5444.398 us; speedup 1.0000x reference)
//
#include <hip/hip_runtime.h>

typedef float v2f __attribute__((ext_vector_type(2)));
typedef float v4f __attribute__((ext_vector_type(4)));

#define N_IN   131072
#define K_EMB  1024
#define D_EMB  64
#define QUANT_OFF 1
#define PERP_OFF  (1 + N_IN * D_EMB)      /* 8388609 */
#define ENC_OFF   (PERP_OFF + 1)          /* 8388610: byte offset %16==8 -> float2 stores only */

// ws layout (4-byte units):
//   [0..1023]    counts (u32)
//   [1024]       loss accumulator (f32)
//   [2048..3071] half squared norms of codes (f32)

__global__ __launch_bounds__(256) void k_prep(const float* __restrict__ emb,
                                              float* __restrict__ ws) {
  int k = blockIdx.x * 256 + threadIdx.x;  // grid=4 -> k in [0,1024)
  ((unsigned int*)ws)[k] = 0u;
  if (k == 0) ws[1024] = 0.0f;
  const float* e = emb + (size_t)k * D_EMB;
  double s = 0.0;
  #pragma unroll
  for (int d = 0; d < D_EMB; ++d) { double v = (double)e[d]; s += v * v; }
  ws[2048 + k] = (float)(0.5 * s);
}

// Block = 64 samples x 4 K-groups (each wave one K-group: code index stays
// wave-uniform -> codes live in SGPRs via s_load, x stays in 64 VGPRs).
// R2 failure mode: 512 blocks -> only 8 waves/CU -> scalar-load latency
// unhidden (VALUBusy 23%). 2048 blocks + VGPR<=73 -> ~28 waves/CU.
__global__ __launch_bounds__(256, 7) void k_main(const float* __restrict__ xg,
                                                 const float* __restrict__ emb,
                                                 float* __restrict__ out,
                                                 float* __restrict__ ws) {
  __shared__ float sc_sh[256];
  __shared__ int   id_sh[256];
  __shared__ float red[256];

  const int tid = threadIdx.x;
  const int s   = tid & 63;     // sample slot
  const int g   = tid >> 6;     // K-group (== wave id)
  const size_t row = (size_t)blockIdx.x * 64 + s;

  // x fully register-resident: 16 x float4
  v4f xr[16];
  const v4f* xp = (const v4f*)(xg + row * D_EMB);
  #pragma unroll
  for (int j = 0; j < 16; ++j) xr[j] = xp[j];

  const float* hn = ws + 2048;
  const v4f* eb = (const v4f*)emb;
  const int k0 = g << 8;        // 256 codes per group

  float best = 3.4e38f;
  int   bidx = k0;

  // depth-2 pipeline: cva holds code k, cvb holds code k+1
  v4f cva[16], cvb[16];
  float ha, hb;
  {
    const v4f* p = eb + ((size_t)k0 << 4);
    #pragma unroll
    for (int j = 0; j < 16; ++j) cva[j] = p[j];
    ha = hn[k0];
  }

  #pragma unroll 1
  for (int kk = 0; kk < 256; kk += 2) {
    const int k = k0 + kk;
    {
      const v4f* p = eb + ((size_t)(k + 1) << 4);
      #pragma unroll
      for (int j = 0; j < 16; ++j) cvb[j] = p[j];
      hb = hn[k + 1];
    }
    {
      v4f acc; acc.x = 0.f; acc.y = 0.f; acc.z = 0.f; acc.w = 0.f;
      #pragma unroll
      for (int j = 0; j < 16; ++j) {
        acc.x = fmaf(xr[j].x, cva[j].x, acc.x);
        acc.y = fmaf(xr[j].y, cva[j].y, acc.y);
        acc.z = fmaf(xr[j].z, cva[j].z, acc.z);
        acc.w = fmaf(xr[j].w, cva[j].w, acc.w);
      }
      float dot = (acc.x + acc.y) + (acc.z + acc.w);
      float sc  = ha - dot;                    // 0.5||e||^2 - x.e
      bool c = sc < best;                      // strict <: lowest k wins ties
      best = c ? sc : best;
      bidx = c ? k : bidx;
    }
    {
      const v4f* p = eb + ((size_t)(k0 + ((kk + 2) & 255)) << 4);
      #pragma unroll
      for (int j = 0; j < 16; ++j) cva[j] = p[j];
      ha = hn[k0 + ((kk + 2) & 255)];
    }
    {
      v4f acc; acc.x = 0.f; acc.y = 0.f; acc.z = 0.f; acc.w = 0.f;
      #pragma unroll
      for (int j = 0; j < 16; ++j) {
        acc.x = fmaf(xr[j].x, cvb[j].x, acc.x);
        acc.y = fmaf(xr[j].y, cvb[j].y, acc.y);
        acc.z = fmaf(xr[j].z, cvb[j].z, acc.z);
        acc.w = fmaf(xr[j].w, cvb[j].w, acc.w);
      }
      float dot = (acc.x + acc.y) + (acc.z + acc.w);
      float sc  = hb - dot;
      bool c = sc < best;
      best = c ? sc : best;
      bidx = c ? (k + 1) : bidx;
    }
  }

  sc_sh[tid] = best;
  id_sh[tid] = bidx;
  __syncthreads();

  // 4-way merge: ascending g + strict < preserves argmin-first tie rule
  float lsum = 0.0f;
  if (tid < 64) {
    float b = sc_sh[tid];
    int   bi = id_sh[tid];
    #pragma unroll
    for (int gg = 1; gg < 4; ++gg) {
      float sg = sc_sh[tid + gg * 64];
      int   ig = id_sh[tid + gg * 64];
      if (sg < b) { b = sg; bi = ig; }
    }
    id_sh[tid] = bi;
    atomicAdd((unsigned int*)ws + bi, 1u);
    // thread tid<64 has g=0, s=tid -> its xr IS sample tid's x
    const v4f* ebest = eb + ((size_t)bi << 4);
    #pragma unroll
    for (int j = 0; j < 16; ++j) {
      v4f ev = ebest[j];
      float dx;
      dx = ev.x - xr[j].x; lsum = fmaf(dx, dx, lsum);
      dx = ev.y - xr[j].y; lsum = fmaf(dx, dx, lsum);
      dx = ev.z - xr[j].z; lsum = fmaf(dx, dx, lsum);
      dx = ev.w - xr[j].w; lsum = fmaf(dx, dx, lsum);
    }
  }
  red[tid] = lsum;
  __syncthreads();
  #pragma unroll
  for (int off = 128; off > 0; off >>= 1) {
    if (tid < off) red[tid] += red[tid + off];
    __syncthreads();
  }
  if (tid == 0) atomicAdd(ws + 1024, red[0]);

  // ---- cooperative coalesced quantized write (64 rows x 64) ----
  float* qblk = out + QUANT_OFF + (size_t)blockIdx.x * (64 * 64);
  const float* xblk = xg + (size_t)blockIdx.x * (64 * 64);
  #pragma unroll 1
  for (int it = 0; it < 16; ++it) {
    int f = it * 256 + tid;
    int r = f >> 6, d = f & 63;
    float ev = emb[((size_t)id_sh[r] << 6) + d];
    float xv = xblk[f];
    __builtin_nontemporal_store(xv + (ev - xv), qblk + f);
  }

  // ---- cooperative coalesced encodings write (64 rows x 1024, one-hot) ----
  v2f* eblk = (v2f*)(out + ENC_OFF) + (size_t)blockIdx.x * (64 * 512);
  #pragma unroll 1
  for (int r = 0; r < 64; ++r) {
    int hit = id_sh[r];           // broadcast LDS read
    int hc  = hit >> 1;
    v2f one; one.x = (hit & 1) ? 0.0f : 1.0f; one.y = (hit & 1) ? 1.0f : 0.0f;
    v2f zer; zer.x = 0.0f; zer.y = 0.0f;
    v2f* rowp = eblk + (size_t)r * 512;
    __builtin_nontemporal_store((hc == tid)       ? one : zer, rowp + tid);
    __builtin_nontemporal_store((hc == tid + 256) ? one : zer, rowp + tid + 256);
  }
}

__global__ __launch_bounds__(256) void k_fin(float* __restrict__ out,
                                             const float* __restrict__ ws) {
  __shared__ float red[256];
  const unsigned int* counts = (const unsigned int*)ws;
  int t = threadIdx.x;
  float s = 0.0f;
  #pragma unroll
  for (int i = 0; i < 4; ++i) {
    float p = (float)counts[t + i * 256] * (1.0f / (float)N_IN);
    s += p * __logf(p + 1e-10f);
  }
  red[t] = s;
  __syncthreads();
  #pragma unroll
  for (int off = 128; off > 0; off >>= 1) {
    if (t < off) red[t] += red[t + off];
    __syncthreads();
  }
  if (t == 0) {
    out[PERP_OFF] = __expf(-red[0]);
    out[0] = 0.25f * ws[1024] * (1.0f / (float)(N_IN * D_EMB));
  }
}

extern "C" void kernel_launch(void* const* d_in, const int* in_sizes, int n_in,
                              void* d_out, int out_size, void* d_ws, size_t ws_size,
                              hipStream_t stream) {
  (void)in_sizes; (void)n_in; (void)out_size; (void)ws_size;
  const float* x   = (const float*)d_in[0];
  const float* emb = (const float*)d_in[1];
  float* out = (float*)d_out;
  float* ws  = (float*)d_ws;

  hipLaunchKernelGGL(k_prep, dim3(4),    dim3(256), 0, stream, emb, ws);
  hipLaunchKernelGGL(k_main, dim3(2048), dim3(256), 0, stream, x, emb, out, ws);
  hipLaunchKernelGGL(k_fin,  dim3(1),    dim3(256), 0, stream, out, ws);
}

// Round 4
// 1477.896 us; speedup vs baseline: 3.6839x; 3.6839x over previous
//
#include <hip/hip_runtime.h>

typedef float v2f __attribute__((ext_vector_type(2)));
typedef float v4f __attribute__((ext_vector_type(4)));

#define N_IN   131072
#define K_EMB  1024
#define D_EMB  64
#define QUANT_OFF 1
#define PERP_OFF  (1 + N_IN * D_EMB)      /* 8388609 */
#define ENC_OFF   (PERP_OFF + 1)          /* 8388610: byte offset %16==8 -> float2 stores only */

// ws layout (4-byte units):
//   [0..1023]    counts (u32)
//   [1024]       loss accumulator (f32)
//   [2048..3071] half squared norms of codes (f32)

__global__ __launch_bounds__(256) void k_prep(const float* __restrict__ emb,
                                              float* __restrict__ ws) {
  int k = blockIdx.x * 256 + threadIdx.x;  // grid=4 -> k in [0,1024)
  ((unsigned int*)ws)[k] = 0u;
  if (k == 0) ws[1024] = 0.0f;
  const float* e = emb + (size_t)k * D_EMB;
  double s = 0.0;
  #pragma unroll
  for (int d = 0; d < D_EMB; ++d) { double v = (double)e[d]; s += v * v; }
  ws[2048 + k] = (float)(0.5 * s);
}

// Block = 64 samples x 4 K-groups (each wave one K-group: code index stays
// wave-uniform -> codes scalarize into SGPRs via s_load; x stays in 64 VGPRs).
// Register-allocation history (the whole game so far):
//   R1 (256,4) cap 128: x rematerialized from global in-loop -> 1177 us
//   R2 (256,2) cap 256: VGPR=72, codes in SGPRs -> 766 us but grid-limited
//                        to 8 waves/CU (512 blocks), latency-unhidden
//   R3 (256,7) cap ~73: total spill to scratch (FETCH 9 GB!) -> 5477 us
// R4 = R3's 2048-block shape + R2's (256,2): VGPR~72 allows 7 waves/SIMD
// from ACTUAL usage; the declaration only promises 2.
__global__ __launch_bounds__(256, 2) void k_main(const float* __restrict__ xg,
                                                 const float* __restrict__ emb,
                                                 float* __restrict__ out,
                                                 float* __restrict__ ws) {
  __shared__ float sc_sh[256];
  __shared__ int   id_sh[256];
  __shared__ float red[256];

  const int tid = threadIdx.x;
  const int s   = tid & 63;     // sample slot
  const int g   = tid >> 6;     // K-group (== wave id)
  const size_t row = (size_t)blockIdx.x * 64 + s;

  // x fully register-resident: 16 x float4
  v4f xr[16];
  const v4f* xp = (const v4f*)(xg + row * D_EMB);
  #pragma unroll
  for (int j = 0; j < 16; ++j) xr[j] = xp[j];

  const float* hn = ws + 2048;
  const v4f* eb = (const v4f*)emb;
  const int k0 = g << 8;        // 256 codes per group

  float best = 3.4e38f;
  int   bidx = k0;

  // depth-2 pipeline: cva holds code k, cvb holds code k+1 (SGPR-resident)
  v4f cva[16], cvb[16];
  float ha, hb;
  {
    const v4f* p = eb + ((size_t)k0 << 4);
    #pragma unroll
    for (int j = 0; j < 16; ++j) cva[j] = p[j];
    ha = hn[k0];
  }

  #pragma unroll 1
  for (int kk = 0; kk < 256; kk += 2) {
    const int k = k0 + kk;
    {
      const v4f* p = eb + ((size_t)(k + 1) << 4);
      #pragma unroll
      for (int j = 0; j < 16; ++j) cvb[j] = p[j];
      hb = hn[k + 1];
    }
    {
      v4f acc; acc.x = 0.f; acc.y = 0.f; acc.z = 0.f; acc.w = 0.f;
      #pragma unroll
      for (int j = 0; j < 16; ++j) {
        acc.x = fmaf(xr[j].x, cva[j].x, acc.x);
        acc.y = fmaf(xr[j].y, cva[j].y, acc.y);
        acc.z = fmaf(xr[j].z, cva[j].z, acc.z);
        acc.w = fmaf(xr[j].w, cva[j].w, acc.w);
      }
      float dot = (acc.x + acc.y) + (acc.z + acc.w);
      float sc  = ha - dot;                    // 0.5||e||^2 - x.e
      bool c = sc < best;                      // strict <: lowest k wins ties
      best = c ? sc : best;
      bidx = c ? k : bidx;
    }
    {
      const v4f* p = eb + ((size_t)(k0 + ((kk + 2) & 255)) << 4);
      #pragma unroll
      for (int j = 0; j < 16; ++j) cva[j] = p[j];
      ha = hn[k0 + ((kk + 2) & 255)];
    }
    {
      v4f acc; acc.x = 0.f; acc.y = 0.f; acc.z = 0.f; acc.w = 0.f;
      #pragma unroll
      for (int j = 0; j < 16; ++j) {
        acc.x = fmaf(xr[j].x, cvb[j].x, acc.x);
        acc.y = fmaf(xr[j].y, cvb[j].y, acc.y);
        acc.z = fmaf(xr[j].z, cvb[j].z, acc.z);
        acc.w = fmaf(xr[j].w, cvb[j].w, acc.w);
      }
      float dot = (acc.x + acc.y) + (acc.z + acc.w);
      float sc  = hb - dot;
      bool c = sc < best;
      best = c ? sc : best;
      bidx = c ? (k + 1) : bidx;
    }
  }

  sc_sh[tid] = best;
  id_sh[tid] = bidx;
  __syncthreads();

  // 4-way merge: ascending g + strict < preserves argmin-first tie rule
  float lsum = 0.0f;
  if (tid < 64) {
    float b = sc_sh[tid];
    int   bi = id_sh[tid];
    #pragma unroll
    for (int gg = 1; gg < 4; ++gg) {
      float sg = sc_sh[tid + gg * 64];
      int   ig = id_sh[tid + gg * 64];
      if (sg < b) { b = sg; bi = ig; }
    }
    id_sh[tid] = bi;
    atomicAdd((unsigned int*)ws + bi, 1u);
    // thread tid<64 has g=0, s=tid -> its xr IS sample tid's x
    const v4f* ebest = eb + ((size_t)bi << 4);
    #pragma unroll
    for (int j = 0; j < 16; ++j) {
      v4f ev = ebest[j];
      float dx;
      dx = ev.x - xr[j].x; lsum = fmaf(dx, dx, lsum);
      dx = ev.y - xr[j].y; lsum = fmaf(dx, dx, lsum);
      dx = ev.z - xr[j].z; lsum = fmaf(dx, dx, lsum);
      dx = ev.w - xr[j].w; lsum = fmaf(dx, dx, lsum);
    }
  }
  red[tid] = lsum;
  __syncthreads();
  #pragma unroll
  for (int off = 128; off > 0; off >>= 1) {
    if (tid < off) red[tid] += red[tid + off];
    __syncthreads();
  }
  if (tid == 0) atomicAdd(ws + 1024, red[0]);

  // ---- cooperative coalesced quantized write (64 rows x 64) ----
  float* qblk = out + QUANT_OFF + (size_t)blockIdx.x * (64 * 64);
  const float* xblk = xg + (size_t)blockIdx.x * (64 * 64);
  #pragma unroll 1
  for (int it = 0; it < 16; ++it) {
    int f = it * 256 + tid;
    int r = f >> 6, d = f & 63;
    float ev = emb[((size_t)id_sh[r] << 6) + d];
    float xv = xblk[f];
    __builtin_nontemporal_store(xv + (ev - xv), qblk + f);
  }

  // ---- cooperative coalesced encodings write (64 rows x 1024, one-hot) ----
  v2f* eblk = (v2f*)(out + ENC_OFF) + (size_t)blockIdx.x * (64 * 512);
  #pragma unroll 1
  for (int r = 0; r < 64; ++r) {
    int hit = id_sh[r];           // broadcast LDS read
    int hc  = hit >> 1;
    v2f one; one.x = (hit & 1) ? 0.0f : 1.0f; one.y = (hit & 1) ? 1.0f : 0.0f;
    v2f zer; zer.x = 0.0f; zer.y = 0.0f;
    v2f* rowp = eblk + (size_t)r * 512;
    __builtin_nontemporal_store((hc == tid)       ? one : zer, rowp + tid);
    __builtin_nontemporal_store((hc == tid + 256) ? one : zer, rowp + tid + 256);
  }
}

__global__ __launch_bounds__(256) void k_fin(float* __restrict__ out,
                                             const float* __restrict__ ws) {
  __shared__ float red[256];
  const unsigned int* counts = (const unsigned int*)ws;
  int t = threadIdx.x;
  float s = 0.0f;
  #pragma unroll
  for (int i = 0; i < 4; ++i) {
    float p = (float)counts[t + i * 256] * (1.0f / (float)N_IN);
    s += p * __logf(p + 1e-10f);
  }
  red[t] = s;
  __syncthreads();
  #pragma unroll
  for (int off = 128; off > 0; off >>= 1) {
    if (t < off) red[t] += red[t + off];
    __syncthreads();
  }
  if (t == 0) {
    out[PERP_OFF] = __expf(-red[0]);
    out[0] = 0.25f * ws[1024] * (1.0f / (float)(N_IN * D_EMB));
  }
}

extern "C" void kernel_launch(void* const* d_in, const int* in_sizes, int n_in,
                              void* d_out, int out_size, void* d_ws, size_t ws_size,
                              hipStream_t stream) {
  (void)in_sizes; (void)n_in; (void)out_size; (void)ws_size;
  const float* x   = (const float*)d_in[0];
  const float* emb = (const float*)d_in[1];
  float* out = (float*)d_out;
  float* ws  = (float*)d_ws;

  hipLaunchKernelGGL(k_prep, dim3(4),    dim3(256), 0, stream, emb, ws);
  hipLaunchKernelGGL(k_main, dim3(2048), dim3(256), 0, stream, x, emb, out, ws);
  hipLaunchKernelGGL(k_fin,  dim3(1),    dim3(256), 0, stream, out, ws);
}

// Round 5
// 898.608 us; speedup vs baseline: 6.0587x; 1.6447x over previous
//
#include <hip/hip_runtime.h>

typedef float v2f __attribute__((ext_vector_type(2)));
typedef float v4f __attribute__((ext_vector_type(4)));

#define N_IN   131072
#define K_EMB  1024
#define D_EMB  64
#define QUANT_OFF 1
#define PERP_OFF  (1 + N_IN * D_EMB)      /* 8388609 */
#define ENC_OFF   (PERP_OFF + 1)          /* 8388610: byte offset %16==8 -> float2 stores only */

// ws layout (4-byte units):
//   [0..1023]    counts (u32)
//   [1024]       loss accumulator (f32)
//   [2048..3071] half squared norms of codes (f32)

__global__ __launch_bounds__(256) void k_prep(const float* __restrict__ emb,
                                              float* __restrict__ ws) {
  int k = blockIdx.x * 256 + threadIdx.x;  // grid=4 -> k in [0,1024)
  ((unsigned int*)ws)[k] = 0u;
  if (k == 0) ws[1024] = 0.0f;
  const float* e = emb + (size_t)k * D_EMB;
  double s = 0.0;
  #pragma unroll
  for (int d = 0; d < D_EMB; ++d) { double v = (double)e[d]; s += v * v; }
  ws[2048 + k] = (float)(0.5 * s);
}

// Block = 64 samples x 4 K-groups. Register/uniformity history:
//   R1 (256,4) cap 128: x rematerialized in-loop            -> 1177 us
//   R2 (256,2): SGPR=112 (codes s_load'd!) but 2048 waves   ->  766 us
//   R3 (256,7): total scratch spill (FETCH 9 GB)            -> 5477 us
//   R4 (256,2)+4-way: k0 = f(tid) -> divergence analysis killed the
//       scalarization (SGPR=32, VGPR=116, per-lane vector loads) -> 1083 us
// R5: readfirstlane(k0) forces wave-uniformity -> code loads return to
// s_load (scalar cache, no VALU issue) while keeping 8192 waves.
__global__ __launch_bounds__(256, 2) void k_main(const float* __restrict__ xg,
                                                 const float* __restrict__ emb,
                                                 float* __restrict__ out,
                                                 float* __restrict__ ws) {
  __shared__ float sc_sh[256];
  __shared__ int   id_sh[256];
  __shared__ float red[256];

  const int tid = threadIdx.x;
  const int s   = tid & 63;     // sample slot (lane)
  const size_t row = (size_t)blockIdx.x * 64 + s;

  // x fully register-resident: 16 x float4
  v4f xr[16];
  const v4f* xp = (const v4f*)(xg + row * D_EMB);
  #pragma unroll
  for (int j = 0; j < 16; ++j) xr[j] = xp[j];

  const float* hn = ws + 2048;
  const v4f* eb = (const v4f*)emb;
  // wave id is uniform in fact; readfirstlane makes it uniform BY DEFINITION
  // so the codebook loads scalarize to s_load.
  const int k0 = __builtin_amdgcn_readfirstlane((tid >> 6) << 8);

  float best = 3.4e38f;
  int   bidx = k0;

  // depth-2 pipeline: cva holds code k, cvb holds code k+1 (SGPR-resident)
  v4f cva[16], cvb[16];
  float ha, hb;
  {
    const v4f* p = eb + ((size_t)k0 << 4);
    #pragma unroll
    for (int j = 0; j < 16; ++j) cva[j] = p[j];
    ha = hn[k0];
  }

  #pragma unroll 1
  for (int kk = 0; kk < 256; kk += 2) {
    const int k = k0 + kk;
    {
      const v4f* p = eb + ((size_t)(k + 1) << 4);
      #pragma unroll
      for (int j = 0; j < 16; ++j) cvb[j] = p[j];
      hb = hn[k + 1];
    }
    {
      v4f acc; acc.x = 0.f; acc.y = 0.f; acc.z = 0.f; acc.w = 0.f;
      #pragma unroll
      for (int j = 0; j < 16; ++j) {
        acc.x = fmaf(xr[j].x, cva[j].x, acc.x);
        acc.y = fmaf(xr[j].y, cva[j].y, acc.y);
        acc.z = fmaf(xr[j].z, cva[j].z, acc.z);
        acc.w = fmaf(xr[j].w, cva[j].w, acc.w);
      }
      float dot = (acc.x + acc.y) + (acc.z + acc.w);
      float sc  = ha - dot;                    // 0.5||e||^2 - x.e
      bool c = sc < best;                      // strict <: lowest k wins ties
      best = c ? sc : best;
      bidx = c ? k : bidx;
    }
    {
      const v4f* p = eb + ((size_t)(k0 + ((kk + 2) & 255)) << 4);
      #pragma unroll
      for (int j = 0; j < 16; ++j) cva[j] = p[j];
      ha = hn[k0 + ((kk + 2) & 255)];
    }
    {
      v4f acc; acc.x = 0.f; acc.y = 0.f; acc.z = 0.f; acc.w = 0.f;
      #pragma unroll
      for (int j = 0; j < 16; ++j) {
        acc.x = fmaf(xr[j].x, cvb[j].x, acc.x);
        acc.y = fmaf(xr[j].y, cvb[j].y, acc.y);
        acc.z = fmaf(xr[j].z, cvb[j].z, acc.z);
        acc.w = fmaf(xr[j].w, cvb[j].w, acc.w);
      }
      float dot = (acc.x + acc.y) + (acc.z + acc.w);
      float sc  = hb - dot;
      bool c = sc < best;
      best = c ? sc : best;
      bidx = c ? (k + 1) : bidx;
    }
  }

  sc_sh[tid] = best;
  id_sh[tid] = bidx;
  __syncthreads();

  // 4-way merge: ascending g + strict < preserves argmin-first tie rule
  float lsum = 0.0f;
  if (tid < 64) {
    float b = sc_sh[tid];
    int   bi = id_sh[tid];
    #pragma unroll
    for (int gg = 1; gg < 4; ++gg) {
      float sg = sc_sh[tid + gg * 64];
      int   ig = id_sh[tid + gg * 64];
      if (sg < b) { b = sg; bi = ig; }
    }
    id_sh[tid] = bi;
    atomicAdd((unsigned int*)ws + bi, 1u);
    // thread tid<64 has g=0, s=tid -> its xr IS sample tid's x
    const v4f* ebest = eb + ((size_t)bi << 4);
    #pragma unroll
    for (int j = 0; j < 16; ++j) {
      v4f ev = ebest[j];
      float dx;
      dx = ev.x - xr[j].x; lsum = fmaf(dx, dx, lsum);
      dx = ev.y - xr[j].y; lsum = fmaf(dx, dx, lsum);
      dx = ev.z - xr[j].z; lsum = fmaf(dx, dx, lsum);
      dx = ev.w - xr[j].w; lsum = fmaf(dx, dx, lsum);
    }
  }
  red[tid] = lsum;
  __syncthreads();
  #pragma unroll
  for (int off = 128; off > 0; off >>= 1) {
    if (tid < off) red[tid] += red[tid + off];
    __syncthreads();
  }
  if (tid == 0) atomicAdd(ws + 1024, red[0]);

  // ---- cooperative coalesced quantized write (64 rows x 64) ----
  float* qblk = out + QUANT_OFF + (size_t)blockIdx.x * (64 * 64);
  const float* xblk = xg + (size_t)blockIdx.x * (64 * 64);
  #pragma unroll 1
  for (int it = 0; it < 16; ++it) {
    int f = it * 256 + tid;
    int r = f >> 6, d = f & 63;
    float ev = emb[((size_t)id_sh[r] << 6) + d];
    float xv = xblk[f];
    __builtin_nontemporal_store(xv + (ev - xv), qblk + f);
  }

  // ---- cooperative coalesced encodings write (64 rows x 1024, one-hot) ----
  v2f* eblk = (v2f*)(out + ENC_OFF) + (size_t)blockIdx.x * (64 * 512);
  #pragma unroll 1
  for (int r = 0; r < 64; ++r) {
    int hit = id_sh[r];           // broadcast LDS read
    int hc  = hit >> 1;
    v2f one; one.x = (hit & 1) ? 0.0f : 1.0f; one.y = (hit & 1) ? 1.0f : 0.0f;
    v2f zer; zer.x = 0.0f; zer.y = 0.0f;
    v2f* rowp = eblk + (size_t)r * 512;
    __builtin_nontemporal_store((hc == tid)       ? one : zer, rowp + tid);
    __builtin_nontemporal_store((hc == tid + 256) ? one : zer, rowp + tid + 256);
  }
}

__global__ __launch_bounds__(256) void k_fin(float* __restrict__ out,
                                             const float* __restrict__ ws) {
  __shared__ float red[256];
  const unsigned int* counts = (const unsigned int*)ws;
  int t = threadIdx.x;
  float s = 0.0f;
  #pragma unroll
  for (int i = 0; i < 4; ++i) {
    float p = (float)counts[t + i * 256] * (1.0f / (float)N_IN);
    s += p * __logf(p + 1e-10f);
  }
  red[t] = s;
  __syncthreads();
  #pragma unroll
  for (int off = 128; off > 0; off >>= 1) {
    if (t < off) red[t] += red[t + off];
    __syncthreads();
  }
  if (t == 0) {
    out[PERP_OFF] = __expf(-red[0]);
    out[0] = 0.25f * ws[1024] * (1.0f / (float)(N_IN * D_EMB));
  }
}

extern "C" void kernel_launch(void* const* d_in, const int* in_sizes, int n_in,
                              void* d_out, int out_size, void* d_ws, size_t ws_size,
                              hipStream_t stream) {
  (void)in_sizes; (void)n_in; (void)out_size; (void)ws_size;
  const float* x   = (const float*)d_in[0];
  const float* emb = (const float*)d_in[1];
  float* out = (float*)d_out;
  float* ws  = (float*)d_ws;

  hipLaunchKernelGGL(k_prep, dim3(4),    dim3(256), 0, stream, emb, ws);
  hipLaunchKernelGGL(k_main, dim3(2048), dim3(256), 0, stream, x, emb, out, ws);
  hipLaunchKernelGGL(k_fin,  dim3(1),    dim3(256), 0, stream, out, ws);
}